// Round 6
// baseline (302.645 us; speedup 1.0000x reference)
//
#include <hip/hip_runtime.h>
#include <cstdint>

// ---------------------------------------------------------------------------
// AttentionSelector: selected = softmax(query @ (x@Wk^T+bk)^T) @ x
// R6: evidence: qt=2 tile => 136 persistent VGPR => 2 waves/SIMD hard cap;
//     all structures land ~190us. Remaining lever = latency exposure per tile.
//     (a) X fragments now register-double-buffered like K: all 11 loads for
//         tile t+1 issue a full tile (~1800 cyc) before use. Was: X loaded
//         ~300-400 cyc before PV use => exposed L2 latency every tile.
//     (b) Part+combine deleted: flash atomicAdds partials into Acc[8192][68]
//         (device-scope fp32), tiny normalize kernel divides by col 66.
//         Kills a 35 MB read-pass + one dispatch. Acc zeroed by memsetAsync.
// ---------------------------------------------------------------------------

typedef __bf16    bf16x4 __attribute__((ext_vector_type(4)));
typedef __bf16    bf16x8 __attribute__((ext_vector_type(8)));
typedef _Float16  f16x4  __attribute__((ext_vector_type(4)));
typedef _Float16  f16x8  __attribute__((ext_vector_type(8)));
typedef float     f32x16 __attribute__((ext_vector_type(16)));

extern "C" __device__ float __ocml_native_exp2_f32(float);

#define NUM_PAIRS   65536
#define NUM_Q       8192
#define DIM         66
#define QPITCH      80        // Qh row pitch (f16)
#define KFT         2560      // Kf f16 per 32-pair tile (5 kk x 512)
#define XFT         3072      // Xf bf16 per 32-pair tile (6 c x 512)
#define ACCP        68        // Acc row pitch (floats); col 66 = denominator
#define NTILES      (NUM_PAIRS/32)   // 2048

__device__ __forceinline__ f32x16 mfma_bf16(bf16x8 a, bf16x8 b, f32x16 c) {
    return __builtin_amdgcn_mfma_f32_32x32x16_bf16(a, b, c, 0, 0, 0);
}
__device__ __forceinline__ f32x16 mfma_f16(f16x8 a, f16x8 b, f32x16 c) {
    return __builtin_amdgcn_mfma_f32_32x32x16_f16(a, b, c, 0, 0, 0);
}
// gfx950: exchange lanes 32..63 of a with lanes 0..31 of b.
__device__ __forceinline__ void plswap(unsigned &a, unsigned &b) {
    asm("v_permlane32_swap_b32 %0, %1" : "+v"(a), "+v"(b));
}
__device__ __forceinline__ unsigned packbf(float a, float b) {
    union { __bf16 h[2]; unsigned u; } t;
    t.h[0] = (__bf16)a; t.h[1] = (__bf16)b;
    return t.u;
}
union U4 { unsigned u[4]; bf16x8 v; };

// Sᵀ C-tile (col=query l31, row(pair)=(r&3)+8*(r>>2)+4h) -> exp2 -> two PV
// A-frags (par0: pairs 0..15, par1: 16..31) via permlane32_swap (verified R2-R5).
__device__ __forceinline__ void makefrags(const f32x16 &s, U4 *f) {
    float P[16];
    #pragma unroll
    for (int r = 0; r < 16; ++r) P[r] = __ocml_native_exp2_f32(s[r]);
    unsigned E0 = packbf(P[0],  P[1]),  E1 = packbf(P[2],  P[3]);
    unsigned F0 = packbf(P[4],  P[5]),  F1 = packbf(P[6],  P[7]);
    plswap(E0, F0); plswap(E1, F1);
    f[0].u[0] = E0; f[0].u[1] = E1; f[0].u[2] = F0; f[0].u[3] = F1;
    unsigned G0 = packbf(P[8],  P[9]),  G1 = packbf(P[10], P[11]);
    unsigned H0 = packbf(P[12], P[13]), H1 = packbf(P[14], P[15]);
    plswap(G0, H0); plswap(G1, H1);
    f[1].u[0] = G0; f[1].u[1] = G1; f[1].u[2] = H0; f[1].u[3] = H1;
}

__device__ __forceinline__ void compute_tile(const f16x8 (&kc)[5], const bf16x8 (&xa)[6],
                                             const f16x8 (&aQ)[2][5], f32x16 (&o)[2][3]) {
    f32x16 s0 = {}, s1 = {};
    #pragma unroll
    for (int kk = 0; kk < 5; ++kk) {
        s0 = mfma_f16(kc[kk], aQ[0][kk], s0);
        s1 = mfma_f16(kc[kk], aQ[1][kk], s1);
    }
    U4 f0[2], f1[2];
    makefrags(s0, f0);
    makefrags(s1, f1);
    #pragma unroll
    for (int par = 0; par < 2; ++par)
        #pragma unroll
        for (int dt = 0; dt < 3; ++dt) {
            o[0][dt] = mfma_bf16(f0[par].v, xa[par * 3 + dt], o[0][dt]);
            o[1][dt] = mfma_bf16(f1[par].v, xa[par * 3 + dt], o[1][dt]);
        }
}

// ---------------------------------------------------------------------------
// Prep: blocks 0..511 -> 128 pairs each: K = x@Wk^T+bk (mfma f16), emit Kf
//       fragment stream + Xf fragment stream. Blocks 512..1023 -> Qh.
// ---------------------------------------------------------------------------
#define PAP 104   // sxh/sW pitch (f16)
#define SKP 88    // sK pitch (f16)
__global__ __launch_bounds__(256) void prep_kernel(
    const float* __restrict__ x, const float* __restrict__ query,
    const float* __restrict__ Wk, const float* __restrict__ bk,
    unsigned short* __restrict__ Kf_u, unsigned short* __restrict__ Xf_u,
    unsigned short* __restrict__ Qh_u) {
    const int tid = threadIdx.x;
    if (blockIdx.x >= 512) {
        _Float16* Qh = (_Float16*)Qh_u;
        int base = (blockIdx.x - 512) * 1280;      // 8192*80/512
        #pragma unroll
        for (int k = 0; k < 5; ++k) {
            int idx = base + k * 256 + tid;
            int q = idx / QPITCH, c = idx % QPITCH;
            float v = (c < DIM) ? query[(long)q * DIM + c] * 1.4426950408889634f : 0.f;
            Qh[idx] = (_Float16)v;
        }
        return;
    }
    _Float16* Kf = (_Float16*)Kf_u;
    __bf16*   Xf = (__bf16*)Xf_u;
    __shared__ _Float16 sxh[128 * PAP];   // x rows (f16), k-padded
    __shared__ _Float16 sW[96 * PAP];     // Wk rows (f16), padded
    __shared__ _Float16 sK[128 * SKP];    // K results [pair][feature]
    const long n0 = (long)blockIdx.x * 128;

    for (int i = tid; i < 128 * 96; i += 256) {
        int r = i / 96, c = i % 96;
        sxh[r * PAP + c] = (_Float16)((c < DIM) ? x[(n0 + r) * DIM + c] : 0.f);
    }
    for (int i = tid; i < 96 * 96; i += 256) {
        int cc = i / 96, d = i % 96;
        sW[cc * PAP + d] = (_Float16)((cc < DIM && d < DIM) ? Wk[cc * DIM + d] : 0.f);
    }
    __syncthreads();

    const int lane = tid & 63, w = tid >> 6;
    const int l31 = lane & 31, h = lane >> 5;

    #pragma unroll
    for (int nt = 0; nt < 3; ++nt) {
        f32x16 acc = {};
        #pragma unroll
        for (int kk = 0; kk < 6; ++kk) {
            f16x8 a = *(const f16x8*)&sxh[(w * 32 + l31) * PAP + kk * 16 + h * 8];
            f16x8 b = *(const f16x8*)&sW[(nt * 32 + l31) * PAP + kk * 16 + h * 8];
            acc = mfma_f16(a, b, acc);
        }
        int c = nt * 32 + l31;
        float bkv = (c < DIM) ? bk[c] : 0.f;
        if (c < SKP) {
            #pragma unroll
            for (int r = 0; r < 16; ++r) {
                int row = (r & 3) + 8 * (r >> 2) + 4 * h;
                sK[(w * 32 + row) * SKP + c] = (_Float16)(acc[r] + bkv);
            }
        }
    }
    __syncthreads();

    // Kf emission: [tile][kk][lane][8]
    for (int i = 0; i < 5; ++i) {
        int slot = i * 256 + tid;
        int tt = slot / 320, rem = slot % 320;
        int kk = rem / 64, l = rem % 64;
        const _Float16* src = &sK[(32 * tt + (l & 31)) * SKP + kk * 16 + (l >> 5) * 8];
        f16x4 lo = *(const f16x4*)src;
        f16x4 hi = *(const f16x4*)(src + 4);
        f16x8 v = __builtin_shufflevector(lo, hi, 0, 1, 2, 3, 4, 5, 6, 7);
        *(f16x8*)&Kf[((long)blockIdx.x * 4 + tt) * KFT + kk * 512 + l * 8] = v;
    }
    // Xf emission: [tile][c=par*3+dt][lane][8] ; content X^T[d][pair]
    for (int i = 0; i < 6; ++i) {
        int slot = i * 256 + tid;
        int tt = slot / 384, rem = slot % 384;
        int c = rem / 64, l = rem % 64;
        int dt = c % 3, par = c / 3;
        int d = 32 * dt + (l & 31);
        int p0 = 32 * tt + 16 * par + 8 * (l >> 5);
        bf16x8 v;
        #pragma unroll
        for (int j = 0; j < 8; ++j) {
            float vv = 0.f;
            if (d < DIM) vv = (float)sxh[(p0 + j) * PAP + d];
            else if (d == DIM) vv = 1.f;
            v[j] = (__bf16)vv;
        }
        *(bf16x8*)&Xf[((long)blockIdx.x * 4 + tt) * XFT + c * 512 + l * 8] = v;
    }
}

// ---------------------------------------------------------------------------
// Flash: grid = 32 qblocks * NS; 256 thr = 4 waves x 64 q (qt=2). No LDS.
// Per 32-pair tile: 11 coalesced dwordx4 frag loads (K AND X both issued one
// full tile ahead, reg-double-buffered), 22 mfma. Epilogue: atomicAdd into Acc.
// ---------------------------------------------------------------------------
__global__ __launch_bounds__(256, 2) void flash_kernel(
    const unsigned short* __restrict__ Qh_u, const unsigned short* __restrict__ Kf_u,
    const unsigned short* __restrict__ Xf_u, float* __restrict__ Acc, int NS) {
    const _Float16* Qh = (const _Float16*)Qh_u;
    const _Float16* Kf = (const _Float16*)Kf_u;
    const __bf16*   Xf = (const __bf16*)Xf_u;

    const int tid = threadIdx.x;
    const int lane = tid & 63, wave = tid >> 6;
    const int l31 = lane & 31, h = lane >> 5;
    const int qb = blockIdx.x / NS, ns = blockIdx.x % NS;
    const int tiles = NTILES / NS;            // 128 at NS=16 (even)
    const int qbase = qb * 256 + wave * 64;

    const _Float16* kf = Kf + (long)(ns * tiles) * KFT + lane * 8;
    const __bf16*   xf = Xf + (long)(ns * tiles) * XFT + lane * 8;

    f16x8 aQ[2][5];
    #pragma unroll
    for (int qt = 0; qt < 2; ++qt)
        #pragma unroll
        for (int kk = 0; kk < 5; ++kk)
            aQ[qt][kk] = *(const f16x8*)&Qh[(long)(qbase + qt * 32 + l31) * QPITCH + kk * 16 + h * 8];

    f32x16 o[2][3] = {};

    f16x8  kA[5], kB[5];
    bf16x8 xA[6], xB[6];
    #pragma unroll
    for (int kk = 0; kk < 5; ++kk) kA[kk] = *(const f16x8*)(kf + kk * 512);
    #pragma unroll
    for (int c = 0; c < 6; ++c)    xA[c]  = *(const bf16x8*)(xf + c * 512);

    for (int t = 0; t < tiles; t += 2) {
        if ((t & 31) == 0) asm volatile("s_barrier");   // drift bound, no drain
        {   // prefetch tile t+1 -> B
            const _Float16* kp = kf + (long)(t + 1) * KFT;
            const __bf16*   xp = xf + (long)(t + 1) * XFT;
            #pragma unroll
            for (int kk = 0; kk < 5; ++kk) kB[kk] = *(const f16x8*)(kp + kk * 512);
            #pragma unroll
            for (int c = 0; c < 6; ++c)    xB[c]  = *(const bf16x8*)(xp + c * 512);
        }
        compute_tile(kA, xA, aQ, o);
        if (t + 2 < tiles) {   // prefetch tile t+2 -> A
            const _Float16* kp = kf + (long)(t + 2) * KFT;
            const __bf16*   xp = xf + (long)(t + 2) * XFT;
            #pragma unroll
            for (int kk = 0; kk < 5; ++kk) kA[kk] = *(const f16x8*)(kp + kk * 512);
            #pragma unroll
            for (int c = 0; c < 6; ++c)    xA[c]  = *(const bf16x8*)(xp + c * 512);
        }
        compute_tile(kB, xB, aQ, o);
    }

    // epilogue: accumulate unnormalized partials; col 66 = denominator
    #pragma unroll
    for (int qt = 0; qt < 2; ++qt)
        #pragma unroll
        for (int dt = 0; dt < 3; ++dt)
            #pragma unroll
            for (int r = 0; r < 16; ++r) {
                int row = (r & 3) + 8 * (r >> 2) + 4 * h;
                int q = qbase + qt * 32 + row;
                int d = dt * 32 + l31;
                if (d < DIM + 1)
                    atomicAdd(&Acc[(long)q * ACCP + d], o[qt][dt][r]);
            }
}

// ---------------------------------------------------------------------------
// Normalize: out[q][d] = Acc[q][d] / Acc[q][66]
// ---------------------------------------------------------------------------
__global__ __launch_bounds__(256) void norm_kernel(
    const float* __restrict__ Acc, float* __restrict__ out) {
    int idx = blockIdx.x * 256 + threadIdx.x;
    if (idx >= NUM_Q * DIM) return;
    int q = idx / DIM, d = idx - q * DIM;
    out[idx] = Acc[q * ACCP + d] / Acc[q * ACCP + DIM];
}

// ---------------------------------------------------------------------------
// Workspace: Qh @0 (1,310,720 B) ; Kf @1,310,720 (10,485,760 B) ;
//            Xf @11,796,480 (12,582,912 B) ; Acc @24,379,392 (2,228,224 B)
// ---------------------------------------------------------------------------
extern "C" void kernel_launch(void* const* d_in, const int* in_sizes, int n_in,
                              void* d_out, int out_size, void* d_ws, size_t ws_size,
                              hipStream_t stream) {
    const float* x     = (const float*)d_in[0];
    const float* query = (const float*)d_in[1];
    const float* Wk    = (const float*)d_in[2];
    const float* bk    = (const float*)d_in[3];
    float* out = (float*)d_out;
    char* ws = (char*)d_ws;

    unsigned short* Qh = (unsigned short*)(ws + 0);
    unsigned short* Kf = (unsigned short*)(ws + 1310720);
    unsigned short* Xf = (unsigned short*)(ws + 11796480);
    float* Acc         = (float*)(ws + 24379392);

    const int NS = 16;

    hipMemsetAsync(Acc, 0, (size_t)NUM_Q * ACCP * 4, stream);
    prep_kernel<<<1024, 256, 0, stream>>>(x, query, Wk, bk, Kf, Xf, Qh);
    flash_kernel<<<(NUM_Q / 256) * NS, 256, 0, stream>>>(Qh, Kf, Xf, Acc, NS);
    norm_kernel<<<(NUM_Q * DIM + 255) / 256, 256, 0, stream>>>(Acc, out);
}

// Round 7
// 296.761 us; speedup vs baseline: 1.0198x; 1.0198x over previous
//
#include <hip/hip_runtime.h>
#include <cstdint>

// ---------------------------------------------------------------------------
// AttentionSelector: selected = softmax(query @ (x@Wk^T+bk)^T) @ x
// R7: de-convoy. R6 evidence: wall ~= SUM of pipe-busy (loads ~80us + trans
//     ~40 + mfma ~19 + valu ~20 ~= 160-190us observed) not MAX -> pipes not
//     overlapping because s_barrier forced all waves into phase lockstep
//     (all load together, all mfma together, all exp2 together).
//     (a) no barrier; wave w walks its 128-tile chunk CIRCULARLY from tile
//         w*32 -> waves permanently in different phases, pipes overlap.
//     (b) epilogue back to Part[q][NS][68] + combine (R6 atomics cost ~20us:
//         WRITE_SIZE 37->43.5MB, 16-way/address cross-XCD contention).
//     (c) keep K+X register double-buffering (R6).
// ---------------------------------------------------------------------------

typedef __bf16    bf16x4 __attribute__((ext_vector_type(4)));
typedef __bf16    bf16x8 __attribute__((ext_vector_type(8)));
typedef _Float16  f16x4  __attribute__((ext_vector_type(4)));
typedef _Float16  f16x8  __attribute__((ext_vector_type(8)));
typedef float     f32x16 __attribute__((ext_vector_type(16)));

extern "C" __device__ float __ocml_native_exp2_f32(float);

#define NUM_PAIRS   65536
#define NUM_Q       8192
#define DIM         66
#define QPITCH      80        // Qh row pitch (f16)
#define KFT         2560      // Kf f16 per 32-pair tile (5 kk x 512)
#define XFT         3072      // Xf bf16 per 32-pair tile (6 c x 512)
#define PARTP       68        // partial row pitch (floats)
#define NTILES      (NUM_PAIRS/32)   // 2048

__device__ __forceinline__ f32x16 mfma_bf16(bf16x8 a, bf16x8 b, f32x16 c) {
    return __builtin_amdgcn_mfma_f32_32x32x16_bf16(a, b, c, 0, 0, 0);
}
__device__ __forceinline__ f32x16 mfma_f16(f16x8 a, f16x8 b, f32x16 c) {
    return __builtin_amdgcn_mfma_f32_32x32x16_f16(a, b, c, 0, 0, 0);
}
// gfx950: exchange lanes 32..63 of a with lanes 0..31 of b.
__device__ __forceinline__ void plswap(unsigned &a, unsigned &b) {
    asm("v_permlane32_swap_b32 %0, %1" : "+v"(a), "+v"(b));
}
__device__ __forceinline__ unsigned packbf(float a, float b) {
    union { __bf16 h[2]; unsigned u; } t;
    t.h[0] = (__bf16)a; t.h[1] = (__bf16)b;
    return t.u;
}
union U4 { unsigned u[4]; bf16x8 v; };

// Sᵀ C-tile (col=query l31, row(pair)=(r&3)+8*(r>>2)+4h) -> exp2 -> two PV
// A-frags (par0: pairs 0..15, par1: 16..31) via permlane32_swap (verified R2-R6).
__device__ __forceinline__ void makefrags(const f32x16 &s, U4 *f) {
    float P[16];
    #pragma unroll
    for (int r = 0; r < 16; ++r) P[r] = __ocml_native_exp2_f32(s[r]);
    unsigned E0 = packbf(P[0],  P[1]),  E1 = packbf(P[2],  P[3]);
    unsigned F0 = packbf(P[4],  P[5]),  F1 = packbf(P[6],  P[7]);
    plswap(E0, F0); plswap(E1, F1);
    f[0].u[0] = E0; f[0].u[1] = E1; f[0].u[2] = F0; f[0].u[3] = F1;
    unsigned G0 = packbf(P[8],  P[9]),  G1 = packbf(P[10], P[11]);
    unsigned H0 = packbf(P[12], P[13]), H1 = packbf(P[14], P[15]);
    plswap(G0, H0); plswap(G1, H1);
    f[1].u[0] = G0; f[1].u[1] = G1; f[1].u[2] = H0; f[1].u[3] = H1;
}

__device__ __forceinline__ void compute_tile(const f16x8 (&kc)[5], const bf16x8 (&xa)[6],
                                             const f16x8 (&aQ)[2][5], f32x16 (&o)[2][3]) {
    f32x16 s0 = {}, s1 = {};
    #pragma unroll
    for (int kk = 0; kk < 5; ++kk) {
        s0 = mfma_f16(kc[kk], aQ[0][kk], s0);
        s1 = mfma_f16(kc[kk], aQ[1][kk], s1);
    }
    U4 f0[2], f1[2];
    makefrags(s0, f0);
    makefrags(s1, f1);
    #pragma unroll
    for (int par = 0; par < 2; ++par)
        #pragma unroll
        for (int dt = 0; dt < 3; ++dt) {
            o[0][dt] = mfma_bf16(f0[par].v, xa[par * 3 + dt], o[0][dt]);
            o[1][dt] = mfma_bf16(f1[par].v, xa[par * 3 + dt], o[1][dt]);
        }
}

// ---------------------------------------------------------------------------
// Prep: blocks 0..511 -> 128 pairs each: K = x@Wk^T+bk (mfma f16), emit Kf
//       fragment stream + Xf fragment stream. Blocks 512..1023 -> Qh.
// ---------------------------------------------------------------------------
#define PAP 104   // sxh/sW pitch (f16)
#define SKP 88    // sK pitch (f16)
__global__ __launch_bounds__(256) void prep_kernel(
    const float* __restrict__ x, const float* __restrict__ query,
    const float* __restrict__ Wk, const float* __restrict__ bk,
    unsigned short* __restrict__ Kf_u, unsigned short* __restrict__ Xf_u,
    unsigned short* __restrict__ Qh_u) {
    const int tid = threadIdx.x;
    if (blockIdx.x >= 512) {
        _Float16* Qh = (_Float16*)Qh_u;
        int base = (blockIdx.x - 512) * 1280;      // 8192*80/512
        #pragma unroll
        for (int k = 0; k < 5; ++k) {
            int idx = base + k * 256 + tid;
            int q = idx / QPITCH, c = idx % QPITCH;
            float v = (c < DIM) ? query[(long)q * DIM + c] * 1.4426950408889634f : 0.f;
            Qh[idx] = (_Float16)v;
        }
        return;
    }
    _Float16* Kf = (_Float16*)Kf_u;
    __bf16*   Xf = (__bf16*)Xf_u;
    __shared__ _Float16 sxh[128 * PAP];   // x rows (f16), k-padded
    __shared__ _Float16 sW[96 * PAP];     // Wk rows (f16), padded
    __shared__ _Float16 sK[128 * SKP];    // K results [pair][feature]
    const long n0 = (long)blockIdx.x * 128;

    for (int i = tid; i < 128 * 96; i += 256) {
        int r = i / 96, c = i % 96;
        sxh[r * PAP + c] = (_Float16)((c < DIM) ? x[(n0 + r) * DIM + c] : 0.f);
    }
    for (int i = tid; i < 96 * 96; i += 256) {
        int cc = i / 96, d = i % 96;
        sW[cc * PAP + d] = (_Float16)((cc < DIM && d < DIM) ? Wk[cc * DIM + d] : 0.f);
    }
    __syncthreads();

    const int lane = tid & 63, w = tid >> 6;
    const int l31 = lane & 31, h = lane >> 5;

    #pragma unroll
    for (int nt = 0; nt < 3; ++nt) {
        f32x16 acc = {};
        #pragma unroll
        for (int kk = 0; kk < 6; ++kk) {
            f16x8 a = *(const f16x8*)&sxh[(w * 32 + l31) * PAP + kk * 16 + h * 8];
            f16x8 b = *(const f16x8*)&sW[(nt * 32 + l31) * PAP + kk * 16 + h * 8];
            acc = mfma_f16(a, b, acc);
        }
        int c = nt * 32 + l31;
        float bkv = (c < DIM) ? bk[c] : 0.f;
        if (c < SKP) {
            #pragma unroll
            for (int r = 0; r < 16; ++r) {
                int row = (r & 3) + 8 * (r >> 2) + 4 * h;
                sK[(w * 32 + row) * SKP + c] = (_Float16)(acc[r] + bkv);
            }
        }
    }
    __syncthreads();

    // Kf emission: [tile][kk][lane][8]
    for (int i = 0; i < 5; ++i) {
        int slot = i * 256 + tid;
        int tt = slot / 320, rem = slot % 320;
        int kk = rem / 64, l = rem % 64;
        const _Float16* src = &sK[(32 * tt + (l & 31)) * SKP + kk * 16 + (l >> 5) * 8];
        f16x4 lo = *(const f16x4*)src;
        f16x4 hi = *(const f16x4*)(src + 4);
        f16x8 v = __builtin_shufflevector(lo, hi, 0, 1, 2, 3, 4, 5, 6, 7);
        *(f16x8*)&Kf[((long)blockIdx.x * 4 + tt) * KFT + kk * 512 + l * 8] = v;
    }
    // Xf emission: [tile][c=par*3+dt][lane][8] ; content X^T[d][pair]
    for (int i = 0; i < 6; ++i) {
        int slot = i * 256 + tid;
        int tt = slot / 384, rem = slot % 384;
        int c = rem / 64, l = rem % 64;
        int dt = c % 3, par = c / 3;
        int d = 32 * dt + (l & 31);
        int p0 = 32 * tt + 16 * par + 8 * (l >> 5);
        bf16x8 v;
        #pragma unroll
        for (int j = 0; j < 8; ++j) {
            float vv = 0.f;
            if (d < DIM) vv = (float)sxh[(p0 + j) * PAP + d];
            else if (d == DIM) vv = 1.f;
            v[j] = (__bf16)vv;
        }
        *(bf16x8*)&Xf[((long)blockIdx.x * 4 + tt) * XFT + c * 512 + l * 8] = v;
    }
}

// ---------------------------------------------------------------------------
// Flash: grid = 32 qblocks * NS; 256 thr = 4 waves x 64 q (qt=2). No LDS, no
// barriers. Wave w walks its chunk's 128 tiles circularly from tile w*32 so
// waves stay phase-staggered (load/mfma/exp2 phases overlap across waves).
// K+X register double-buffered, one full tile of prefetch lead.
// ---------------------------------------------------------------------------
__global__ __launch_bounds__(256, 2) void flash_kernel(
    const unsigned short* __restrict__ Qh_u, const unsigned short* __restrict__ Kf_u,
    const unsigned short* __restrict__ Xf_u, float* __restrict__ Part, int NS) {
    const _Float16* Qh = (const _Float16*)Qh_u;
    const _Float16* Kf = (const _Float16*)Kf_u;
    const __bf16*   Xf = (const __bf16*)Xf_u;

    const int tid = threadIdx.x;
    const int lane = tid & 63, wave = tid >> 6;
    const int l31 = lane & 31, h = lane >> 5;
    const int qb = blockIdx.x / NS, ns = blockIdx.x % NS;
    const int tiles = NTILES / NS;            // 128 at NS=16 (pow2)
    const int tmask = tiles - 1;
    const int qbase = qb * 256 + wave * 64;
    const int slip = wave * (tiles >> 2);     // 0,32,64,96: phase stagger

    const _Float16* kf = Kf + (long)(ns * tiles) * KFT + lane * 8;
    const __bf16*   xf = Xf + (long)(ns * tiles) * XFT + lane * 8;

    f16x8 aQ[2][5];
    #pragma unroll
    for (int qt = 0; qt < 2; ++qt)
        #pragma unroll
        for (int kk = 0; kk < 5; ++kk)
            aQ[qt][kk] = *(const f16x8*)&Qh[(long)(qbase + qt * 32 + l31) * QPITCH + kk * 16 + h * 8];

    f32x16 o[2][3] = {};

    f16x8  kA[5], kB[5];
    bf16x8 xA[6], xB[6];
    {
        const _Float16* kp = kf + (long)slip * KFT;
        const __bf16*   xp = xf + (long)slip * XFT;
        #pragma unroll
        for (int kk = 0; kk < 5; ++kk) kA[kk] = *(const f16x8*)(kp + kk * 512);
        #pragma unroll
        for (int c = 0; c < 6; ++c)    xA[c]  = *(const bf16x8*)(xp + c * 512);
    }

    for (int i = 0; i < tiles; i += 2) {
        {   // prefetch tile slip+i+1 -> B
            int t1 = (slip + i + 1) & tmask;
            const _Float16* kp = kf + (long)t1 * KFT;
            const __bf16*   xp = xf + (long)t1 * XFT;
            #pragma unroll
            for (int kk = 0; kk < 5; ++kk) kB[kk] = *(const f16x8*)(kp + kk * 512);
            #pragma unroll
            for (int c = 0; c < 6; ++c)    xB[c]  = *(const bf16x8*)(xp + c * 512);
        }
        compute_tile(kA, xA, aQ, o);
        {   // prefetch tile slip+i+2 -> A
            int t2 = (slip + i + 2) & tmask;
            const _Float16* kp = kf + (long)t2 * KFT;
            const __bf16*   xp = xf + (long)t2 * XFT;
            #pragma unroll
            for (int kk = 0; kk < 5; ++kk) kA[kk] = *(const f16x8*)(kp + kk * 512);
            #pragma unroll
            for (int c = 0; c < 6; ++c)    xA[c]  = *(const bf16x8*)(xp + c * 512);
        }
        compute_tile(kB, xB, aQ, o);
    }

    // epilogue: unnormalized partials, layout [q][NS][68]; col 66 = denom
    #pragma unroll
    for (int qt = 0; qt < 2; ++qt)
        #pragma unroll
        for (int dt = 0; dt < 3; ++dt)
            #pragma unroll
            for (int r = 0; r < 16; ++r) {
                int row = (r & 3) + 8 * (r >> 2) + 4 * h;
                int q = qbase + qt * 32 + row;
                int d = dt * 32 + l31;
                if (d < DIM + 1)
                    Part[((long)q * NS + ns) * PARTP + d] = o[qt][dt][r];
            }
}

// ---------------------------------------------------------------------------
// Combine: out[q][d] = sum_s Part[q][s][d] / sum_s Part[q][s][66]
// Part rows for one q are contiguous (NS*272 B).
// ---------------------------------------------------------------------------
__global__ __launch_bounds__(256) void combine_kernel(
    const float* __restrict__ Part, float* __restrict__ out, int NS) {
    int q = blockIdx.x * 2 + (threadIdx.x >> 7);
    int d = threadIdx.x & 127;
    if (d >= DIM) return;
    const float* base = Part + (long)q * NS * PARTP;
    float num = 0.f, den = 0.f;
    #pragma unroll 4
    for (int s = 0; s < NS; ++s) {
        num += base[s * PARTP + d];
        den += base[s * PARTP + DIM];
    }
    out[(long)q * DIM + d] = num / den;
}

// ---------------------------------------------------------------------------
// Workspace: Qh @0 (1,310,720 B) ; Kf @1,310,720 (10,485,760 B) ;
//            Xf @11,796,480 (12,582,912 B) ; Part @24,379,392 (8192*NS*68*4)
// ---------------------------------------------------------------------------
extern "C" void kernel_launch(void* const* d_in, const int* in_sizes, int n_in,
                              void* d_out, int out_size, void* d_ws, size_t ws_size,
                              hipStream_t stream) {
    const float* x     = (const float*)d_in[0];
    const float* query = (const float*)d_in[1];
    const float* Wk    = (const float*)d_in[2];
    const float* bk    = (const float*)d_in[3];
    float* out = (float*)d_out;
    char* ws = (char*)d_ws;

    unsigned short* Qh = (unsigned short*)(ws + 0);
    unsigned short* Kf = (unsigned short*)(ws + 1310720);
    unsigned short* Xf = (unsigned short*)(ws + 11796480);
    float* Part        = (float*)(ws + 24379392);

    const int NS = 16;

    prep_kernel<<<1024, 256, 0, stream>>>(x, query, Wk, bk, Kf, Xf, Qh);
    flash_kernel<<<(NUM_Q / 256) * NS, 256, 0, stream>>>(Qh, Kf, Xf, Part, NS);
    combine_kernel<<<NUM_Q / 2, 256, 0, stream>>>(Part, out, NS);
}

// Round 9
// 279.816 us; speedup vs baseline: 1.0816x; 1.0606x over previous
//
#include <hip/hip_runtime.h>
#include <cstdint>

// ---------------------------------------------------------------------------
// AttentionSelector: selected = softmax(query @ (x@Wk^T+bk)^T) @ x
// R9: R8 with the transpose bug fixed. scores = q·(Wk x + bk) = (Wk^T q)·x
//     + q·bk (softmax-invariant const). R8 computed Wk q instead of Wk^T q
//     (dotted rows instead of columns) -> absmax 5.8. Fix: store Wk
//     TRANSPOSED into LDS (sWq[e][d] = Wk[d][e]); dot loop unchanged.
//     Everything else identical to R8:
//     - Qh = (Wk^T q) * log2e (f16), flash streams raw x (f16) as S-operand.
//     - flash: no LDS/barriers/stagger, reg-double-buffered frag streams.
// ---------------------------------------------------------------------------

typedef __bf16    bf16x4 __attribute__((ext_vector_type(4)));
typedef __bf16    bf16x8 __attribute__((ext_vector_type(8)));
typedef _Float16  f16x4  __attribute__((ext_vector_type(4)));
typedef _Float16  f16x8  __attribute__((ext_vector_type(8)));
typedef float     f32x16 __attribute__((ext_vector_type(16)));

extern "C" __device__ float __ocml_native_exp2_f32(float);

#define NUM_PAIRS   65536
#define NUM_Q       8192
#define DIM         66
#define QPITCH      80        // Qh row pitch (f16)
#define KFT         2560      // Af f16 per 32-pair tile (5 kk x 512)
#define XFT         3072      // Xf bf16 per 32-pair tile (6 c x 512)
#define PARTP       68        // partial row pitch (floats)
#define NTILES      (NUM_PAIRS/32)   // 2048

__device__ __forceinline__ f32x16 mfma_bf16(bf16x8 a, bf16x8 b, f32x16 c) {
    return __builtin_amdgcn_mfma_f32_32x32x16_bf16(a, b, c, 0, 0, 0);
}
__device__ __forceinline__ f32x16 mfma_f16(f16x8 a, f16x8 b, f32x16 c) {
    return __builtin_amdgcn_mfma_f32_32x32x16_f16(a, b, c, 0, 0, 0);
}
// gfx950: exchange lanes 32..63 of a with lanes 0..31 of b.
__device__ __forceinline__ void plswap(unsigned &a, unsigned &b) {
    asm("v_permlane32_swap_b32 %0, %1" : "+v"(a), "+v"(b));
}
__device__ __forceinline__ unsigned packbf(float a, float b) {
    union { __bf16 h[2]; unsigned u; } t;
    t.h[0] = (__bf16)a; t.h[1] = (__bf16)b;
    return t.u;
}
union U4 { unsigned u[4]; bf16x8 v; };

// Sᵀ C-tile (col=query l31, row(pair)=(r&3)+8*(r>>2)+4h) -> exp2 -> two PV
// A-frags (par0: pairs 0..15, par1: 16..31) via permlane32_swap (verified R2-R7).
__device__ __forceinline__ void makefrags(const f32x16 &s, U4 *f) {
    float P[16];
    #pragma unroll
    for (int r = 0; r < 16; ++r) P[r] = __ocml_native_exp2_f32(s[r]);
    unsigned E0 = packbf(P[0],  P[1]),  E1 = packbf(P[2],  P[3]);
    unsigned F0 = packbf(P[4],  P[5]),  F1 = packbf(P[6],  P[7]);
    plswap(E0, F0); plswap(E1, F1);
    f[0].u[0] = E0; f[0].u[1] = E1; f[0].u[2] = F0; f[0].u[3] = F1;
    unsigned G0 = packbf(P[8],  P[9]),  G1 = packbf(P[10], P[11]);
    unsigned H0 = packbf(P[12], P[13]), H1 = packbf(P[14], P[15]);
    plswap(G0, H0); plswap(G1, H1);
    f[1].u[0] = G0; f[1].u[1] = G1; f[1].u[2] = H0; f[1].u[3] = H1;
}

__device__ __forceinline__ void compute_tile(const f16x8 (&kc)[5], const bf16x8 (&xa)[6],
                                             const f16x8 (&aQ)[2][5], f32x16 (&o)[2][3]) {
    f32x16 s0 = {}, s1 = {};
    #pragma unroll
    for (int kk = 0; kk < 5; ++kk) {
        s0 = mfma_f16(kc[kk], aQ[0][kk], s0);
        s1 = mfma_f16(kc[kk], aQ[1][kk], s1);
    }
    U4 f0[2], f1[2];
    makefrags(s0, f0);
    makefrags(s1, f1);
    #pragma unroll
    for (int par = 0; par < 2; ++par)
        #pragma unroll
        for (int dt = 0; dt < 3; ++dt) {
            o[0][dt] = mfma_bf16(f0[par].v, xa[par * 3 + dt], o[0][dt]);
            o[1][dt] = mfma_bf16(f1[par].v, xa[par * 3 + dt], o[1][dt]);
        }
}

// ---------------------------------------------------------------------------
// Prep: blocks 0..511  -> 128 pairs each: transpose/cast x into Af (f16
//       S-operand frags, d-padded to 80) + Xf (bf16 PV frags, row 66 = ones).
//       blocks 512..1023 -> 16 queries each: Qh = (Wk^T q) * log2e (f16).
// ---------------------------------------------------------------------------
#define PAP 104   // sxh pitch (f16)
#define WQP 67    // sWq/sq pitch (f32): odd -> conflict-free
__global__ __launch_bounds__(256) void prep_kernel(
    const float* __restrict__ x, const float* __restrict__ query,
    const float* __restrict__ Wk,
    unsigned short* __restrict__ Af_u, unsigned short* __restrict__ Xf_u,
    unsigned short* __restrict__ Qh_u) {
    const int tid = threadIdx.x;
    if (blockIdx.x >= 512) {
        // ---- query side: q' = Wk^T q, scaled by log2e ----
        __shared__ float sWq[DIM * WQP];   // sWq[e][d] = Wk[d][e]  (TRANSPOSED)
        __shared__ float sq[16 * WQP];
        _Float16* Qh = (_Float16*)Qh_u;
        const int q0 = (blockIdx.x - 512) * 16;
        for (int i = tid; i < DIM * DIM; i += 256)
            sWq[(i % DIM) * WQP + (i / DIM)] = Wk[i];   // R9 FIX: transposed store
        for (int i = tid; i < 16 * DIM; i += 256)
            sq[(i / DIM) * WQP + (i % DIM)] = query[(long)(q0 + i / DIM) * DIM + (i % DIM)];
        __syncthreads();
        for (int slot = tid; slot < 16 * QPITCH; slot += 256) {
            int qi = slot / QPITCH, c = slot % QPITCH;
            float acc = 0.f;
            if (c < DIM) {
                const float* qr = &sq[qi * WQP];
                const float* wr = &sWq[c * WQP];        // row c of Wk^T = col c of Wk
                #pragma unroll 6
                for (int d = 0; d < DIM; ++d) acc += qr[d] * wr[d];
                acc *= 1.4426950408889634f;
            }
            Qh[(long)(q0 + qi) * QPITCH + c] = (_Float16)acc;
        }
        return;
    }
    // ---- pair side: x -> Af (f16 frag stream) + Xf (bf16 transposed frags) ----
    _Float16* Af = (_Float16*)Af_u;
    __bf16*   Xf = (__bf16*)Xf_u;
    __shared__ _Float16 sxh[128 * PAP];   // x rows (f16), cols 66..103 = 0
    const long n0 = (long)blockIdx.x * 128;

    for (int i = tid; i < 128 * 96; i += 256) {
        int r = i / 96, c = i % 96;
        sxh[r * PAP + c] = (_Float16)((c < DIM) ? x[(n0 + r) * DIM + c] : 0.f);
    }
    __syncthreads();

    // Af emission: [tile][kk][lane][8] ; A[m=pair l&31][k=16kk+8(l>>5)+j] = x[pair][k]
    for (int i = 0; i < 5; ++i) {
        int slot = i * 256 + tid;
        int tt = slot / 320, rem = slot % 320;
        int kk = rem / 64, l = rem % 64;
        const _Float16* src = &sxh[(32 * tt + (l & 31)) * PAP + kk * 16 + (l >> 5) * 8];
        f16x4 lo = *(const f16x4*)src;
        f16x4 hi = *(const f16x4*)(src + 4);
        f16x8 v = __builtin_shufflevector(lo, hi, 0, 1, 2, 3, 4, 5, 6, 7);
        *(f16x8*)&Af[((long)blockIdx.x * 4 + tt) * KFT + kk * 512 + l * 8] = v;
    }
    // Xf emission: [tile][c=par*3+dt][lane][8] ; content X^T[d][pair], row 66 = 1
    for (int i = 0; i < 6; ++i) {
        int slot = i * 256 + tid;
        int tt = slot / 384, rem = slot % 384;
        int c = rem / 64, l = rem % 64;
        int dt = c % 3, par = c / 3;
        int d = 32 * dt + (l & 31);
        int p0 = 32 * tt + 16 * par + 8 * (l >> 5);
        bf16x8 v;
        #pragma unroll
        for (int j = 0; j < 8; ++j) {
            float vv = 0.f;
            if (d < DIM) vv = (float)sxh[(p0 + j) * PAP + d];
            else if (d == DIM) vv = 1.f;
            v[j] = (__bf16)vv;
        }
        *(bf16x8*)&Xf[((long)blockIdx.x * 4 + tt) * XFT + c * 512 + l * 8] = v;
    }
}

// ---------------------------------------------------------------------------
// Flash: grid = 32 qblocks * NS; 256 thr = 4 waves x 64 q (qt=2). No LDS, no
// barriers, no stagger (all 4 waves walk the same tiles -> L1 reuse).
// Per 32-pair tile: 11 coalesced dwordx4 frag loads (reg-double-buffered, one
// full tile of prefetch lead), 22 mfma. S-operand = raw x (f16).
// ---------------------------------------------------------------------------
__global__ __launch_bounds__(256, 2) void flash_kernel(
    const unsigned short* __restrict__ Qh_u, const unsigned short* __restrict__ Af_u,
    const unsigned short* __restrict__ Xf_u, float* __restrict__ Part, int NS) {
    const _Float16* Qh = (const _Float16*)Qh_u;
    const _Float16* Af = (const _Float16*)Af_u;
    const __bf16*   Xf = (const __bf16*)Xf_u;

    const int tid = threadIdx.x;
    const int lane = tid & 63, wave = tid >> 6;
    const int l31 = lane & 31, h = lane >> 5;
    const int qb = blockIdx.x / NS, ns = blockIdx.x % NS;
    const int tiles = NTILES / NS;            // 128 at NS=16 (even)
    const int qbase = qb * 256 + wave * 64;

    const _Float16* kf = Af + (long)(ns * tiles) * KFT + lane * 8;
    const __bf16*   xf = Xf + (long)(ns * tiles) * XFT + lane * 8;

    f16x8 aQ[2][5];
    #pragma unroll
    for (int qt = 0; qt < 2; ++qt)
        #pragma unroll
        for (int kk = 0; kk < 5; ++kk)
            aQ[qt][kk] = *(const f16x8*)&Qh[(long)(qbase + qt * 32 + l31) * QPITCH + kk * 16 + h * 8];

    f32x16 o[2][3] = {};

    f16x8  kA[5], kB[5];
    bf16x8 xA[6], xB[6];
    #pragma unroll
    for (int kk = 0; kk < 5; ++kk) kA[kk] = *(const f16x8*)(kf + kk * 512);
    #pragma unroll
    for (int c = 0; c < 6; ++c)    xA[c]  = *(const bf16x8*)(xf + c * 512);

    for (int t = 0; t < tiles; t += 2) {
        {   // prefetch tile t+1 -> B
            const _Float16* kp = kf + (long)(t + 1) * KFT;
            const __bf16*   xp = xf + (long)(t + 1) * XFT;
            #pragma unroll
            for (int kk = 0; kk < 5; ++kk) kB[kk] = *(const f16x8*)(kp + kk * 512);
            #pragma unroll
            for (int c = 0; c < 6; ++c)    xB[c]  = *(const bf16x8*)(xp + c * 512);
        }
        compute_tile(kA, xA, aQ, o);
        if (t + 2 < tiles) {   // prefetch tile t+2 -> A
            const _Float16* kp = kf + (long)(t + 2) * KFT;
            const __bf16*   xp = xf + (long)(t + 2) * XFT;
            #pragma unroll
            for (int kk = 0; kk < 5; ++kk) kA[kk] = *(const f16x8*)(kp + kk * 512);
            #pragma unroll
            for (int c = 0; c < 6; ++c)    xA[c]  = *(const bf16x8*)(xp + c * 512);
        }
        compute_tile(kB, xB, aQ, o);
    }

    // epilogue: unnormalized partials, layout [q][NS][68]; col 66 = denom
    #pragma unroll
    for (int qt = 0; qt < 2; ++qt)
        #pragma unroll
        for (int dt = 0; dt < 3; ++dt)
            #pragma unroll
            for (int r = 0; r < 16; ++r) {
                int row = (r & 3) + 8 * (r >> 2) + 4 * h;
                int q = qbase + qt * 32 + row;
                int d = dt * 32 + l31;
                if (d < DIM + 1)
                    Part[((long)q * NS + ns) * PARTP + d] = o[qt][dt][r];
            }
}

// ---------------------------------------------------------------------------
// Combine: out[q][d] = sum_s Part[q][s][d] / sum_s Part[q][s][66]
// Part rows for one q are contiguous (NS*272 B).
// ---------------------------------------------------------------------------
__global__ __launch_bounds__(256) void combine_kernel(
    const float* __restrict__ Part, float* __restrict__ out, int NS) {
    int q = blockIdx.x * 2 + (threadIdx.x >> 7);
    int d = threadIdx.x & 127;
    if (d >= DIM) return;
    const float* base = Part + (long)q * NS * PARTP;
    float num = 0.f, den = 0.f;
    #pragma unroll 4
    for (int s = 0; s < NS; ++s) {
        num += base[s * PARTP + d];
        den += base[s * PARTP + DIM];
    }
    out[(long)q * DIM + d] = num / den;
}

// ---------------------------------------------------------------------------
// Workspace: Qh @0 (1,310,720 B) ; Af @1,310,720 (10,485,760 B) ;
//            Xf @11,796,480 (12,582,912 B) ; Part @24,379,392 (8192*NS*68*4)
// ---------------------------------------------------------------------------
extern "C" void kernel_launch(void* const* d_in, const int* in_sizes, int n_in,
                              void* d_out, int out_size, void* d_ws, size_t ws_size,
                              hipStream_t stream) {
    const float* x     = (const float*)d_in[0];
    const float* query = (const float*)d_in[1];
    const float* Wk    = (const float*)d_in[2];
    float* out = (float*)d_out;
    char* ws = (char*)d_ws;

    unsigned short* Qh = (unsigned short*)(ws + 0);
    unsigned short* Af = (unsigned short*)(ws + 1310720);
    unsigned short* Xf = (unsigned short*)(ws + 11796480);
    float* Part        = (float*)(ws + 24379392);

    const int NS = 16;

    prep_kernel<<<1024, 256, 0, stream>>>(x, query, Wk, Af, Xf, Qh);
    flash_kernel<<<(NUM_Q / 256) * NS, 256, 0, stream>>>(Qh, Af, Xf, Part, NS);
    combine_kernel<<<NUM_Q / 2, 256, 0, stream>>>(Part, out, NS);
}

// Round 10
// 275.631 us; speedup vs baseline: 1.0980x; 1.0152x over previous
//
#include <hip/hip_runtime.h>
#include <cstdint>

// ---------------------------------------------------------------------------
// AttentionSelector: selected = softmax(query @ (x@Wk^T+bk)^T) @ x
// R10: intra-wave software pipeline. R9 model: wall = per-tile serial chain
//      S-mfma -> exp2+pack -> PV (~430cyc) at 2 waves/SIMD; exp2/pack never
//      overlaps MFMA. Restructure: carry S across iterations; per tile t,
//      makefrags(s_t) [trans/VALU] is adjacent to S-mfma(t+1) [MFMA pipe,
//      independent] -> pipes overlap within one wave.
//      Register budget: X single-buffered (reload after last PV use), K
//      double-buffered, persistent s0/s1 -> ~246 total regs, 2 waves/SIMD.
//      Prep (Wk^T-folded queries, raw-x streams) + combine unchanged from R9.
// ---------------------------------------------------------------------------

typedef __bf16    bf16x4 __attribute__((ext_vector_type(4)));
typedef __bf16    bf16x8 __attribute__((ext_vector_type(8)));
typedef _Float16  f16x4  __attribute__((ext_vector_type(4)));
typedef _Float16  f16x8  __attribute__((ext_vector_type(8)));
typedef float     f32x16 __attribute__((ext_vector_type(16)));

extern "C" __device__ float __ocml_native_exp2_f32(float);

#define NUM_PAIRS   65536
#define NUM_Q       8192
#define DIM         66
#define QPITCH      80        // Qh row pitch (f16)
#define KFT         2560      // Af f16 per 32-pair tile (5 kk x 512)
#define XFT         3072      // Xf bf16 per 32-pair tile (6 c x 512)
#define PARTP       68        // partial row pitch (floats)
#define NTILES      (NUM_PAIRS/32)   // 2048

__device__ __forceinline__ f32x16 mfma_bf16(bf16x8 a, bf16x8 b, f32x16 c) {
    return __builtin_amdgcn_mfma_f32_32x32x16_bf16(a, b, c, 0, 0, 0);
}
__device__ __forceinline__ f32x16 mfma_f16(f16x8 a, f16x8 b, f32x16 c) {
    return __builtin_amdgcn_mfma_f32_32x32x16_f16(a, b, c, 0, 0, 0);
}
// gfx950: exchange lanes 32..63 of a with lanes 0..31 of b.
__device__ __forceinline__ void plswap(unsigned &a, unsigned &b) {
    asm("v_permlane32_swap_b32 %0, %1" : "+v"(a), "+v"(b));
}
__device__ __forceinline__ unsigned packbf(float a, float b) {
    union { __bf16 h[2]; unsigned u; } t;
    t.h[0] = (__bf16)a; t.h[1] = (__bf16)b;
    return t.u;
}
union U4 { unsigned u[4]; bf16x8 v; };

// Sᵀ C-tile (col=query l31, row(pair)=(r&3)+8*(r>>2)+4h) -> exp2 -> two PV
// A-frags (par0: pairs 0..15, par1: 16..31) via permlane32_swap (verified R2-R9).
__device__ __forceinline__ void makefrags(const f32x16 &s, U4 *f) {
    float P[16];
    #pragma unroll
    for (int r = 0; r < 16; ++r) P[r] = __ocml_native_exp2_f32(s[r]);
    unsigned E0 = packbf(P[0],  P[1]),  E1 = packbf(P[2],  P[3]);
    unsigned F0 = packbf(P[4],  P[5]),  F1 = packbf(P[6],  P[7]);
    plswap(E0, F0); plswap(E1, F1);
    f[0].u[0] = E0; f[0].u[1] = E1; f[0].u[2] = F0; f[0].u[3] = F1;
    unsigned G0 = packbf(P[8],  P[9]),  G1 = packbf(P[10], P[11]);
    unsigned H0 = packbf(P[12], P[13]), H1 = packbf(P[14], P[15]);
    plswap(G0, H0); plswap(G1, H1);
    f[1].u[0] = G0; f[1].u[1] = G1; f[1].u[2] = H0; f[1].u[3] = H1;
}

// One pipelined step for tile t:
//   entering: s0,s1 = S(tile t); kNext = k(t+1); xR = x(t)
//   leaving : s0,s1 = S(tile t+1); kPre = k(t+2); xR = x(t+1)
__device__ __forceinline__ void pipe_step(
    int t, int tiles, const _Float16* __restrict__ kf, const __bf16* __restrict__ xf,
    f16x8 (&kPre)[5], const f16x8 (&kNext)[5], bf16x8 (&xR)[6],
    const f16x8 (&aQ)[2][5], f32x16 &s0, f32x16 &s1, f32x16 (&o)[2][3]) {

    {   // prefetch k(t+2) into the dead buffer (k(t) was consumed last iter)
        long tk = (t + 2 < tiles) ? (long)(t + 2) : (long)(tiles - 1);
        const _Float16* kp = kf + tk * KFT;
        #pragma unroll
        for (int kk = 0; kk < 5; ++kk) kPre[kk] = *(const f16x8*)(kp + kk * 512);
    }

    // ---- qt0: trans(t) || S-mfma(t+1) || PV(t) ----
    U4 f0[2];
    makefrags(s0, f0);                 // trans/VALU, consumes s0
    {
        f32x16 ns = {};
        #pragma unroll
        for (int kk = 0; kk < 5; ++kk) ns = mfma_f16(kNext[kk], aQ[0][kk], ns);
        s0 = ns;                       // reuses s0's registers (dead above)
    }
    #pragma unroll
    for (int par = 0; par < 2; ++par)
        #pragma unroll
        for (int dt = 0; dt < 3; ++dt)
            o[0][dt] = mfma_bf16(f0[par].v, xR[par * 3 + dt], o[0][dt]);

    // ---- qt1 ----
    U4 f1[2];
    makefrags(s1, f1);
    {
        f32x16 ns = {};
        #pragma unroll
        for (int kk = 0; kk < 5; ++kk) ns = mfma_f16(kNext[kk], aQ[1][kk], ns);
        s1 = ns;
    }
    #pragma unroll
    for (int par = 0; par < 2; ++par)
        #pragma unroll
        for (int dt = 0; dt < 3; ++dt)
            o[1][dt] = mfma_bf16(f1[par].v, xR[par * 3 + dt], o[1][dt]);

    {   // reload x with tile t+1 (xR's last use was PV1 just above)
        long tx = (t + 1 < tiles) ? (long)(t + 1) : (long)(tiles - 1);
        const __bf16* xp = xf + tx * XFT;
        #pragma unroll
        for (int c = 0; c < 6; ++c) xR[c] = *(const bf16x8*)(xp + c * 512);
    }
}

// ---------------------------------------------------------------------------
// Prep: blocks 0..511  -> 128 pairs each: transpose/cast x into Af (f16
//       S-operand frags, d-padded to 80) + Xf (bf16 PV frags, row 66 = ones).
//       blocks 512..1023 -> 16 queries each: Qh = (Wk^T q) * log2e (f16).
// ---------------------------------------------------------------------------
#define PAP 104   // sxh pitch (f16)
#define WQP 67    // sWq/sq pitch (f32): odd -> conflict-free
__global__ __launch_bounds__(256) void prep_kernel(
    const float* __restrict__ x, const float* __restrict__ query,
    const float* __restrict__ Wk,
    unsigned short* __restrict__ Af_u, unsigned short* __restrict__ Xf_u,
    unsigned short* __restrict__ Qh_u) {
    const int tid = threadIdx.x;
    if (blockIdx.x >= 512) {
        // ---- query side: q' = Wk^T q, scaled by log2e ----
        __shared__ float sWq[DIM * WQP];   // sWq[e][d] = Wk[d][e]  (transposed)
        __shared__ float sq[16 * WQP];
        _Float16* Qh = (_Float16*)Qh_u;
        const int q0 = (blockIdx.x - 512) * 16;
        for (int i = tid; i < DIM * DIM; i += 256)
            sWq[(i % DIM) * WQP + (i / DIM)] = Wk[i];
        for (int i = tid; i < 16 * DIM; i += 256)
            sq[(i / DIM) * WQP + (i % DIM)] = query[(long)(q0 + i / DIM) * DIM + (i % DIM)];
        __syncthreads();
        for (int slot = tid; slot < 16 * QPITCH; slot += 256) {
            int qi = slot / QPITCH, c = slot % QPITCH;
            float acc = 0.f;
            if (c < DIM) {
                const float* qr = &sq[qi * WQP];
                const float* wr = &sWq[c * WQP];
                #pragma unroll 6
                for (int d = 0; d < DIM; ++d) acc += qr[d] * wr[d];
                acc *= 1.4426950408889634f;
            }
            Qh[(long)(q0 + qi) * QPITCH + c] = (_Float16)acc;
        }
        return;
    }
    // ---- pair side: x -> Af (f16 frag stream) + Xf (bf16 transposed frags) ----
    _Float16* Af = (_Float16*)Af_u;
    __bf16*   Xf = (__bf16*)Xf_u;
    __shared__ _Float16 sxh[128 * PAP];   // x rows (f16), cols 66..103 = 0
    const long n0 = (long)blockIdx.x * 128;

    for (int i = tid; i < 128 * 96; i += 256) {
        int r = i / 96, c = i % 96;
        sxh[r * PAP + c] = (_Float16)((c < DIM) ? x[(n0 + r) * DIM + c] : 0.f);
    }
    __syncthreads();

    // Af emission: [tile][kk][lane][8] ; A[m=pair l&31][k=16kk+8(l>>5)+j] = x[pair][k]
    for (int i = 0; i < 5; ++i) {
        int slot = i * 256 + tid;
        int tt = slot / 320, rem = slot % 320;
        int kk = rem / 64, l = rem % 64;
        const _Float16* src = &sxh[(32 * tt + (l & 31)) * PAP + kk * 16 + (l >> 5) * 8];
        f16x4 lo = *(const f16x4*)src;
        f16x4 hi = *(const f16x4*)(src + 4);
        f16x8 v = __builtin_shufflevector(lo, hi, 0, 1, 2, 3, 4, 5, 6, 7);
        *(f16x8*)&Af[((long)blockIdx.x * 4 + tt) * KFT + kk * 512 + l * 8] = v;
    }
    // Xf emission: [tile][c=par*3+dt][lane][8] ; content X^T[d][pair], row 66 = 1
    for (int i = 0; i < 6; ++i) {
        int slot = i * 256 + tid;
        int tt = slot / 384, rem = slot % 384;
        int c = rem / 64, l = rem % 64;
        int dt = c % 3, par = c / 3;
        int d = 32 * dt + (l & 31);
        int p0 = 32 * tt + 16 * par + 8 * (l >> 5);
        bf16x8 v;
        #pragma unroll
        for (int j = 0; j < 8; ++j) {
            float vv = 0.f;
            if (d < DIM) vv = (float)sxh[(p0 + j) * PAP + d];
            else if (d == DIM) vv = 1.f;
            v[j] = (__bf16)vv;
        }
        *(bf16x8*)&Xf[((long)blockIdx.x * 4 + tt) * XFT + c * 512 + l * 8] = v;
    }
}

// ---------------------------------------------------------------------------
// Flash: grid = 32 qblocks * NS; 256 thr = 4 waves x 64 q (qt=2). No LDS, no
// barriers. Software-pipelined: S carried across iterations so trans(t)
// overlaps S-mfma(t+1); K reg-dbuf (1.5-iter lead), X single-buffer.
// ---------------------------------------------------------------------------
__global__ __launch_bounds__(256, 2) void flash_kernel(
    const unsigned short* __restrict__ Qh_u, const unsigned short* __restrict__ Af_u,
    const unsigned short* __restrict__ Xf_u, float* __restrict__ Part, int NS) {
    const _Float16* Qh = (const _Float16*)Qh_u;
    const _Float16* Af = (const _Float16*)Af_u;
    const __bf16*   Xf = (const __bf16*)Xf_u;

    const int tid = threadIdx.x;
    const int lane = tid & 63, wave = tid >> 6;
    const int l31 = lane & 31, h = lane >> 5;
    const int qb = blockIdx.x / NS, ns = blockIdx.x % NS;
    const int tiles = NTILES / NS;            // 128 at NS=16 (even, >=2)
    const int qbase = qb * 256 + wave * 64;

    const _Float16* kf = Af + (long)(ns * tiles) * KFT + lane * 8;
    const __bf16*   xf = Xf + (long)(ns * tiles) * XFT + lane * 8;

    f16x8 aQ[2][5];
    #pragma unroll
    for (int qt = 0; qt < 2; ++qt)
        #pragma unroll
        for (int kk = 0; kk < 5; ++kk)
            aQ[qt][kk] = *(const f16x8*)&Qh[(long)(qbase + qt * 32 + l31) * QPITCH + kk * 16 + h * 8];

    f32x16 o[2][3] = {};
    f16x8  kA[5], kB[5];
    bf16x8 xR[6];
    f32x16 s0, s1;

    // prologue: k(0)->kA, x(0)->xR, k(1)->kB; S(tile 0) from kA
    #pragma unroll
    for (int kk = 0; kk < 5; ++kk) kA[kk] = *(const f16x8*)(kf + kk * 512);
    #pragma unroll
    for (int c = 0; c < 6; ++c)    xR[c]  = *(const bf16x8*)(xf + c * 512);
    #pragma unroll
    for (int kk = 0; kk < 5; ++kk) kB[kk] = *(const f16x8*)(kf + KFT + kk * 512);
    {
        f32x16 a = {}, b = {};
        #pragma unroll
        for (int kk = 0; kk < 5; ++kk) {
            a = mfma_f16(kA[kk], aQ[0][kk], a);
            b = mfma_f16(kA[kk], aQ[1][kk], b);
        }
        s0 = a; s1 = b;
    }

    for (int t = 0; t < tiles; t += 2) {
        pipe_step(t,     tiles, kf, xf, kA, kB, xR, aQ, s0, s1, o);
        pipe_step(t + 1, tiles, kf, xf, kB, kA, xR, aQ, s0, s1, o);
    }

    // epilogue: unnormalized partials, layout [q][NS][68]; col 66 = denom
    #pragma unroll
    for (int qt = 0; qt < 2; ++qt)
        #pragma unroll
        for (int dt = 0; dt < 3; ++dt)
            #pragma unroll
            for (int r = 0; r < 16; ++r) {
                int row = (r & 3) + 8 * (r >> 2) + 4 * h;
                int q = qbase + qt * 32 + row;
                int d = dt * 32 + l31;
                if (d < DIM + 1)
                    Part[((long)q * NS + ns) * PARTP + d] = o[qt][dt][r];
            }
}

// ---------------------------------------------------------------------------
// Combine: out[q][d] = sum_s Part[q][s][d] / sum_s Part[q][s][66]
// Part rows for one q are contiguous (NS*272 B).
// ---------------------------------------------------------------------------
__global__ __launch_bounds__(256) void combine_kernel(
    const float* __restrict__ Part, float* __restrict__ out, int NS) {
    int q = blockIdx.x * 2 + (threadIdx.x >> 7);
    int d = threadIdx.x & 127;
    if (d >= DIM) return;
    const float* base = Part + (long)q * NS * PARTP;
    float num = 0.f, den = 0.f;
    #pragma unroll 4
    for (int s = 0; s < NS; ++s) {
        num += base[s * PARTP + d];
        den += base[s * PARTP + DIM];
    }
    out[(long)q * DIM + d] = num / den;
}

// ---------------------------------------------------------------------------
// Workspace: Qh @0 (1,310,720 B) ; Af @1,310,720 (10,485,760 B) ;
//            Xf @11,796,480 (12,582,912 B) ; Part @24,379,392 (8192*NS*68*4)
// ---------------------------------------------------------------------------
extern "C" void kernel_launch(void* const* d_in, const int* in_sizes, int n_in,
                              void* d_out, int out_size, void* d_ws, size_t ws_size,
                              hipStream_t stream) {
    const float* x     = (const float*)d_in[0];
    const float* query = (const float*)d_in[1];
    const float* Wk    = (const float*)d_in[2];
    float* out = (float*)d_out;
    char* ws = (char*)d_ws;

    unsigned short* Qh = (unsigned short*)(ws + 0);
    unsigned short* Af = (unsigned short*)(ws + 1310720);
    unsigned short* Xf = (unsigned short*)(ws + 11796480);
    float* Part        = (float*)(ws + 24379392);

    const int NS = 16;

    prep_kernel<<<1024, 256, 0, stream>>>(x, query, Wk, Af, Xf, Qh);
    flash_kernel<<<(NUM_Q / 256) * NS, 256, 0, stream>>>(Qh, Af, Xf, Part, NS);
    combine_kernel<<<NUM_Q / 2, 256, 0, stream>>>(Part, out, NS);
}

// Round 11
// 271.337 us; speedup vs baseline: 1.1154x; 1.0158x over previous
//
#include <hip/hip_runtime.h>
#include <cstdint>

// ---------------------------------------------------------------------------
// AttentionSelector: selected = softmax(query @ (x@Wk^T+bk)^T) @ x
// R11: flash is at the m97-class plateau (counted-MFMA 37% of dense, VALU 40%,
//      six structures all ~190-215us) -> attack the ~71us of non-flash time.
//      prep rebuilt:
//      (a) query side q' = (Wk^T q)*log2e via MFMA f16 (64 blocks x 128 q,
//          R5-verified 18-mfma structure; log2e folded into LDS Wk^T). The
//          old scalar dot (660 ds_read/thread) dominated prep.
//      (b) pair side: ones-trick (sxh[r][66]=1.0, pads 0) -> Af unaffected
//          (Q cols 66+ are zero) and Xf emission is branch-free.
//      (c) f32x2 loads (row stride 66 floats = 8B-aligned).
//      flash (R10, verified) + combine unchanged.
// ---------------------------------------------------------------------------

typedef __bf16    bf16x4 __attribute__((ext_vector_type(4)));
typedef __bf16    bf16x8 __attribute__((ext_vector_type(8)));
typedef _Float16  f16x4  __attribute__((ext_vector_type(4)));
typedef _Float16  f16x8  __attribute__((ext_vector_type(8)));
typedef float     f32x2  __attribute__((ext_vector_type(2)));
typedef float     f32x16 __attribute__((ext_vector_type(16)));

extern "C" __device__ float __ocml_native_exp2_f32(float);

#define NUM_PAIRS   65536
#define NUM_Q       8192
#define DIM         66
#define QPITCH      80        // Qh row pitch (f16)
#define KFT         2560      // Af f16 per 32-pair tile (5 kk x 512)
#define XFT         3072      // Xf bf16 per 32-pair tile (6 c x 512)
#define PARTP       68        // partial row pitch (floats)
#define NTILES      (NUM_PAIRS/32)   // 2048

__device__ __forceinline__ f32x16 mfma_bf16(bf16x8 a, bf16x8 b, f32x16 c) {
    return __builtin_amdgcn_mfma_f32_32x32x16_bf16(a, b, c, 0, 0, 0);
}
__device__ __forceinline__ f32x16 mfma_f16(f16x8 a, f16x8 b, f32x16 c) {
    return __builtin_amdgcn_mfma_f32_32x32x16_f16(a, b, c, 0, 0, 0);
}
// gfx950: exchange lanes 32..63 of a with lanes 0..31 of b.
__device__ __forceinline__ void plswap(unsigned &a, unsigned &b) {
    asm("v_permlane32_swap_b32 %0, %1" : "+v"(a), "+v"(b));
}
__device__ __forceinline__ unsigned packbf(float a, float b) {
    union { __bf16 h[2]; unsigned u; } t;
    t.h[0] = (__bf16)a; t.h[1] = (__bf16)b;
    return t.u;
}
union U4 { unsigned u[4]; bf16x8 v; };

// Sᵀ C-tile (col=query l31, row(pair)=(r&3)+8*(r>>2)+4h) -> exp2 -> two PV
// A-frags (par0: pairs 0..15, par1: 16..31) via permlane32_swap (verified R2-R10).
__device__ __forceinline__ void makefrags(const f32x16 &s, U4 *f) {
    float P[16];
    #pragma unroll
    for (int r = 0; r < 16; ++r) P[r] = __ocml_native_exp2_f32(s[r]);
    unsigned E0 = packbf(P[0],  P[1]),  E1 = packbf(P[2],  P[3]);
    unsigned F0 = packbf(P[4],  P[5]),  F1 = packbf(P[6],  P[7]);
    plswap(E0, F0); plswap(E1, F1);
    f[0].u[0] = E0; f[0].u[1] = E1; f[0].u[2] = F0; f[0].u[3] = F1;
    unsigned G0 = packbf(P[8],  P[9]),  G1 = packbf(P[10], P[11]);
    unsigned H0 = packbf(P[12], P[13]), H1 = packbf(P[14], P[15]);
    plswap(G0, H0); plswap(G1, H1);
    f[1].u[0] = G0; f[1].u[1] = G1; f[1].u[2] = H0; f[1].u[3] = H1;
}

// One pipelined flash step for tile t (verified R10).
__device__ __forceinline__ void pipe_step(
    int t, int tiles, const _Float16* __restrict__ kf, const __bf16* __restrict__ xf,
    f16x8 (&kPre)[5], const f16x8 (&kNext)[5], bf16x8 (&xR)[6],
    const f16x8 (&aQ)[2][5], f32x16 &s0, f32x16 &s1, f32x16 (&o)[2][3]) {

    {   // prefetch k(t+2) into the dead buffer
        long tk = (t + 2 < tiles) ? (long)(t + 2) : (long)(tiles - 1);
        const _Float16* kp = kf + tk * KFT;
        #pragma unroll
        for (int kk = 0; kk < 5; ++kk) kPre[kk] = *(const f16x8*)(kp + kk * 512);
    }
    U4 f0[2];
    makefrags(s0, f0);
    {
        f32x16 ns = {};
        #pragma unroll
        for (int kk = 0; kk < 5; ++kk) ns = mfma_f16(kNext[kk], aQ[0][kk], ns);
        s0 = ns;
    }
    #pragma unroll
    for (int par = 0; par < 2; ++par)
        #pragma unroll
        for (int dt = 0; dt < 3; ++dt)
            o[0][dt] = mfma_bf16(f0[par].v, xR[par * 3 + dt], o[0][dt]);

    U4 f1[2];
    makefrags(s1, f1);
    {
        f32x16 ns = {};
        #pragma unroll
        for (int kk = 0; kk < 5; ++kk) ns = mfma_f16(kNext[kk], aQ[1][kk], ns);
        s1 = ns;
    }
    #pragma unroll
    for (int par = 0; par < 2; ++par)
        #pragma unroll
        for (int dt = 0; dt < 3; ++dt)
            o[1][dt] = mfma_bf16(f1[par].v, xR[par * 3 + dt], o[1][dt]);

    {   // reload x with tile t+1 (last use was PV1 above)
        long tx = (t + 1 < tiles) ? (long)(t + 1) : (long)(tiles - 1);
        const __bf16* xp = xf + tx * XFT;
        #pragma unroll
        for (int c = 0; c < 6; ++c) xR[c] = *(const bf16x8*)(xp + c * 512);
    }
}

// ---------------------------------------------------------------------------
// Prep: blocks 0..511 -> 128 pairs each: x -> Af (f16 S-frags) + Xf (bf16 PV
//       frags, ones-trick for row 66). blocks 512..575 -> 128 queries each:
//       Qh = (Wk^T q)*log2e via mfma f16.
// ---------------------------------------------------------------------------
#define PAP 104   // LDS pitch (f16)
__global__ __launch_bounds__(256) void prep_kernel(
    const float* __restrict__ x, const float* __restrict__ query,
    const float* __restrict__ Wk,
    unsigned short* __restrict__ Af_u, unsigned short* __restrict__ Xf_u,
    unsigned short* __restrict__ Qh_u) {
    const int tid = threadIdx.x;
    const int lane = tid & 63, w = tid >> 6;
    const int l31 = lane & 31, h = lane >> 5;

    if (blockIdx.x >= 512) {
        // ---- query side: Qh = (Wk^T q) * log2e via mfma ----
        __shared__ _Float16 sq[128 * PAP];    // query rows f16, pads 0
        __shared__ _Float16 sWT[96 * PAP];    // sWT[e][d] = Wk[d][e]*log2e, pads 0
        _Float16* Qh = (_Float16*)Qh_u;
        const long q0 = (long)(blockIdx.x - 512) * 128;

        // zero pads once (both arrays), then fill
        for (int i = tid; i < (128 + 96) * PAP / 2; i += 256)
            ((unsigned*)sq)[i] = 0u;          // sq and sWT are contiguous? NOT guaranteed.
        __syncthreads();
        // (separate explicit zero for sWT since adjacency isn't guaranteed)
        for (int i = tid; i < 96 * PAP / 2; i += 256)
            ((unsigned*)sWT)[i] = 0u;
        __syncthreads();

        for (int i = tid; i < 128 * 33; i += 256) {       // f32x2 loads
            int r = i / 33, c2 = (i % 33) * 2;
            f32x2 v = *(const f32x2*)&query[(q0 + r) * DIM + c2];
            sq[r * PAP + c2]     = (_Float16)v.x;
            sq[r * PAP + c2 + 1] = (_Float16)v.y;
        }
        for (int i = tid; i < DIM * 33; i += 256) {       // Wk transposed, scaled
            int d = i / 33, e2 = (i % 33) * 2;
            f32x2 v = *(const f32x2*)&Wk[d * DIM + e2];
            sWT[e2 * PAP + d]       = (_Float16)(v.x * 1.4426950408889634f);
            sWT[(e2 + 1) * PAP + d] = (_Float16)(v.y * 1.4426950408889634f);
        }
        __syncthreads();

        #pragma unroll
        for (int nt = 0; nt < 3; ++nt) {
            f32x16 acc = {};
            #pragma unroll
            for (int kk = 0; kk < 6; ++kk) {
                f16x8 a = *(const f16x8*)&sq[(w * 32 + l31) * PAP + kk * 16 + h * 8];
                f16x8 b = *(const f16x8*)&sWT[(nt * 32 + l31) * PAP + kk * 16 + h * 8];
                acc = mfma_f16(a, b, acc);
            }
            int c = nt * 32 + l31;
            if (c < QPITCH) {
                #pragma unroll
                for (int r = 0; r < 16; ++r) {
                    int row = (r & 3) + 8 * (r >> 2) + 4 * h;
                    Qh[(q0 + w * 32 + row) * QPITCH + c] = (_Float16)acc[r];
                }
            }
        }
        return;
    }

    // ---- pair side: x -> Af + Xf ----
    _Float16* Af = (_Float16*)Af_u;
    __bf16*   Xf = (__bf16*)Xf_u;
    __shared__ _Float16 sxh[128 * PAP];   // cols: 0..65 = x, 66 = 1.0, 67.. = 0
    const long n0 = (long)blockIdx.x * 128;

    for (int i = tid; i < 128 * PAP / 2; i += 256) ((unsigned*)sxh)[i] = 0u;
    __syncthreads();
    for (int i = tid; i < 128 * 33; i += 256) {
        int r = i / 33, c2 = (i % 33) * 2;
        f32x2 v = *(const f32x2*)&x[(n0 + r) * DIM + c2];
        sxh[r * PAP + c2]     = (_Float16)v.x;
        sxh[r * PAP + c2 + 1] = (_Float16)v.y;
    }
    for (int r = tid; r < 128; r += 256) sxh[r * PAP + DIM] = (_Float16)1.0f;
    __syncthreads();

    // Af emission: [tile][kk][lane][8] (S-operand; col 66 = 1 is harmless:
    // Qh cols 66..79 are exactly 0)
    for (int i = 0; i < 5; ++i) {
        int slot = i * 256 + tid;
        int tt = slot / 320, rem = slot % 320;
        int kk = rem / 64, l = rem % 64;
        const _Float16* src = &sxh[(32 * tt + (l & 31)) * PAP + kk * 16 + (l >> 5) * 8];
        f16x4 lo = *(const f16x4*)src;
        f16x4 hi = *(const f16x4*)(src + 4);
        f16x8 v = __builtin_shufflevector(lo, hi, 0, 1, 2, 3, 4, 5, 6, 7);
        *(f16x8*)&Af[((long)blockIdx.x * 4 + tt) * KFT + kk * 512 + l * 8] = v;
    }
    // Xf emission (branch-free): [tile][c=par*3+dt][lane][8] = X^T[d][pair]
    for (int i = 0; i < 6; ++i) {
        int slot = i * 256 + tid;
        int tt = slot / 384, rem = slot % 384;
        int c = rem / 64, l = rem % 64;
        int dt = c % 3, par = c / 3;
        int d = 32 * dt + (l & 31);
        int p0 = 32 * tt + 16 * par + 8 * (l >> 5);
        bf16x8 v;
        #pragma unroll
        for (int j = 0; j < 8; ++j)
            v[j] = (__bf16)(float)sxh[(p0 + j) * PAP + d];
        *(bf16x8*)&Xf[((long)blockIdx.x * 4 + tt) * XFT + c * 512 + l * 8] = v;
    }
}

// ---------------------------------------------------------------------------
// Flash: grid = 32 qblocks * NS; 256 thr = 4 waves x 64 q (qt=2). No LDS, no
// barriers. S carried across iterations; K reg-dbuf, X single-buffer.
// ---------------------------------------------------------------------------
__global__ __launch_bounds__(256, 2) void flash_kernel(
    const unsigned short* __restrict__ Qh_u, const unsigned short* __restrict__ Af_u,
    const unsigned short* __restrict__ Xf_u, float* __restrict__ Part, int NS) {
    const _Float16* Qh = (const _Float16*)Qh_u;
    const _Float16* Af = (const _Float16*)Af_u;
    const __bf16*   Xf = (const __bf16*)Xf_u;

    const int tid = threadIdx.x;
    const int lane = tid & 63, wave = tid >> 6;
    const int l31 = lane & 31, h = lane >> 5;
    const int qb = blockIdx.x / NS, ns = blockIdx.x % NS;
    const int tiles = NTILES / NS;            // 128 at NS=16 (even)
    const int qbase = qb * 256 + wave * 64;

    const _Float16* kf = Af + (long)(ns * tiles) * KFT + lane * 8;
    const __bf16*   xf = Xf + (long)(ns * tiles) * XFT + lane * 8;

    f16x8 aQ[2][5];
    #pragma unroll
    for (int qt = 0; qt < 2; ++qt)
        #pragma unroll
        for (int kk = 0; kk < 5; ++kk)
            aQ[qt][kk] = *(const f16x8*)&Qh[(long)(qbase + qt * 32 + l31) * QPITCH + kk * 16 + h * 8];

    f32x16 o[2][3] = {};
    f16x8  kA[5], kB[5];
    bf16x8 xR[6];
    f32x16 s0, s1;

    #pragma unroll
    for (int kk = 0; kk < 5; ++kk) kA[kk] = *(const f16x8*)(kf + kk * 512);
    #pragma unroll
    for (int c = 0; c < 6; ++c)    xR[c]  = *(const bf16x8*)(xf + c * 512);
    #pragma unroll
    for (int kk = 0; kk < 5; ++kk) kB[kk] = *(const f16x8*)(kf + KFT + kk * 512);
    {
        f32x16 a = {}, b = {};
        #pragma unroll
        for (int kk = 0; kk < 5; ++kk) {
            a = mfma_f16(kA[kk], aQ[0][kk], a);
            b = mfma_f16(kA[kk], aQ[1][kk], b);
        }
        s0 = a; s1 = b;
    }

    for (int t = 0; t < tiles; t += 2) {
        pipe_step(t,     tiles, kf, xf, kA, kB, xR, aQ, s0, s1, o);
        pipe_step(t + 1, tiles, kf, xf, kB, kA, xR, aQ, s0, s1, o);
    }

    // epilogue: unnormalized partials, layout [q][NS][68]; col 66 = denom
    #pragma unroll
    for (int qt = 0; qt < 2; ++qt)
        #pragma unroll
        for (int dt = 0; dt < 3; ++dt)
            #pragma unroll
            for (int r = 0; r < 16; ++r) {
                int row = (r & 3) + 8 * (r >> 2) + 4 * h;
                int q = qbase + qt * 32 + row;
                int d = dt * 32 + l31;
                if (d < DIM + 1)
                    Part[((long)q * NS + ns) * PARTP + d] = o[qt][dt][r];
            }
}

// ---------------------------------------------------------------------------
// Combine: out[q][d] = sum_s Part[q][s][d] / sum_s Part[q][s][66]
// ---------------------------------------------------------------------------
__global__ __launch_bounds__(256) void combine_kernel(
    const float* __restrict__ Part, float* __restrict__ out, int NS) {
    int q = blockIdx.x * 2 + (threadIdx.x >> 7);
    int d = threadIdx.x & 127;
    if (d >= DIM) return;
    const float* base = Part + (long)q * NS * PARTP;
    float num = 0.f, den = 0.f;
    #pragma unroll 4
    for (int s = 0; s < NS; ++s) {
        num += base[s * PARTP + d];
        den += base[s * PARTP + DIM];
    }
    out[(long)q * DIM + d] = num / den;
}

// ---------------------------------------------------------------------------
// Workspace: Qh @0 (1,310,720 B) ; Af @1,310,720 (10,485,760 B) ;
//            Xf @11,796,480 (12,582,912 B) ; Part @24,379,392 (8192*NS*68*4)
// ---------------------------------------------------------------------------
extern "C" void kernel_launch(void* const* d_in, const int* in_sizes, int n_in,
                              void* d_out, int out_size, void* d_ws, size_t ws_size,
                              hipStream_t stream) {
    const float* x     = (const float*)d_in[0];
    const float* query = (const float*)d_in[1];
    const float* Wk    = (const float*)d_in[2];
    float* out = (float*)d_out;
    char* ws = (char*)d_ws;

    unsigned short* Qh = (unsigned short*)(ws + 0);
    unsigned short* Af = (unsigned short*)(ws + 1310720);
    unsigned short* Xf = (unsigned short*)(ws + 11796480);
    float* Part        = (float*)(ws + 24379392);

    const int NS = 16;

    prep_kernel<<<512 + NUM_Q / 128, 256, 0, stream>>>(x, query, Wk, Af, Xf, Qh);
    flash_kernel<<<(NUM_Q / 256) * NS, 256, 0, stream>>>(Qh, Af, Xf, Part, NS);
    combine_kernel<<<NUM_Q / 2, 256, 0, stream>>>(Part, out, NS);
}